// Round 14
// baseline (201.989 us; speedup 1.0000x reference)
//
#include <hip/hip_runtime.h>
#include <stdint.h>

#define N_SPK 2048
#define M_UTT 16
#define D_EMB 512
#define NM (N_SPK * M_UTT)
#define FP8_SCALE 16.0f   // quantization scale for fp8 operands (1/256 folded into w)
#define GEMM_BLOCKS 4096

typedef __attribute__((ext_vector_type(4))) float f32x4;
typedef __attribute__((ext_vector_type(4))) int   i32x4;
typedef __attribute__((ext_vector_type(8))) int   i32x8;

__device__ __forceinline__ void async_copy16(const void* g, void* l) {
    __builtin_amdgcn_global_load_lds(
        (const __attribute__((address_space(1))) unsigned int*)g,
        (__attribute__((address_space(3))) unsigned int*)l,
        16, 0, 0);
}

// read one 32B (K=128) MFMA fragment from swizzled LDS: granule 2q of row r at
// slot s0 = 2q ^ (r&7), granule 2q+1 at s0^1. base points at the 128B row.
__device__ __forceinline__ i32x8 ld_frag(const unsigned char* base, int s0) {
    i32x4 lo = *(const i32x4*)(base + s0 * 16);
    i32x4 hi = *(const i32x4*)(base + (s0 ^ 1) * 16);
    return __builtin_shufflevector(lo, hi, 0, 1, 2, 3, 4, 5, 6, 7);
}

// ---------------------------------------------------------------------------
// Kernel A: per-speaker prep (round-7 34KB-LDS version). Zeroes colsum/out,
// and the ticket counter IF the workspace has room for it (done != nullptr).
// ROUND-13 LESSON: rounds 12/13 container crashes were (by elimination) an
// OOB write: `done` lived 4B past the 17MB+256KB workspace the layout was
// originally sized to. Never extend the workspace without checking ws_size.
// ---------------------------------------------------------------------------
__global__ __launch_bounds__(256) void prep_kernel(
    const float* __restrict__ V, const float* __restrict__ wp,
    const float* __restrict__ bp, unsigned char* __restrict__ Cn8,
    unsigned char* __restrict__ vn8, float* __restrict__ dterm,
    float* __restrict__ colsum, float* __restrict__ out,
    int* __restrict__ done)
{
    const int spk = blockIdx.x, t = threadIdx.x;
    const int wave = t >> 6, lane = t & 63;
    const float2* vb = (const float2*)(V + (size_t)spk * (M_UTT * D_EMB)); // [16][256]

    __shared__ __align__(16) float2 red[M_UTT][264];  // {sv,vv} partials (+8 pad)
    __shared__ float red2[32];    // rows 0..15 sv, 16..31 vv
    __shared__ float invs[M_UTT];
    __shared__ float wred[4];

    // folded zeroing of colsum + out (+ ticket counter if present)
    if (spk < 128) colsum[spk * 256 + t] = 0.f;
    if (spk == 0 && t == 0) {
        out[0] = 0.f;
        if (done) done[0] = 0;
    }

    // ---- single global read pass ----
    float2 p[M_UTT];
#pragma unroll
    for (int m = 0; m < M_UTT; ++m) p[m] = vb[m * 256 + t];

    float2 ss = make_float2(0.f, 0.f);
#pragma unroll
    for (int m = 0; m < M_UTT; ++m) { ss.x += p[m].x; ss.y += p[m].y; }

    // ||ssum||^2 butterfly (4 waves -> wred)
    float cnp = ss.x * ss.x + ss.y * ss.y;
#pragma unroll
    for (int off = 32; off > 0; off >>= 1) cnp += __shfl_xor(cnp, off);
    if (lane == 0) wred[wave] = cnp;

    // per-utterance partials -> LDS (packed sv,vv)
#pragma unroll
    for (int m = 0; m < M_UTT; ++m) {
        red[m][t] = make_float2(ss.x * p[m].x + ss.y * p[m].y,      // <ssum, v> part
                                p[m].x * p[m].x + p[m].y * p[m].y); // ||v||^2 part
    }
    __syncthreads();
    const float cn2 = wred[0] + wred[1] + wred[2] + wred[3];

    // ---- batched row reduction: 16 threads per row, 8 float4 each ----
    {
        const int r = t >> 4, s = t & 15;
        const float4* rp = (const float4*)red;   // row stride = 132 float4
        float sv = 0.f, vvs = 0.f;
#pragma unroll
        for (int k = 0; k < 8; ++k) {
            float4 q = rp[r * 132 + s + 16 * k]; // {sv0,vv0,sv1,vv1}
            sv  += q.x + q.z;
            vvs += q.y + q.w;
        }
        sv  += __shfl_xor(sv, 1);  vvs += __shfl_xor(vvs, 1);
        sv  += __shfl_xor(sv, 2);  vvs += __shfl_xor(vvs, 2);
        sv  += __shfl_xor(sv, 4);  vvs += __shfl_xor(vvs, 4);
        sv  += __shfl_xor(sv, 8);  vvs += __shfl_xor(vvs, 8);
        if (s == 0) { red2[r] = sv; red2[r + 16] = vvs; }
    }
    __syncthreads();

    // ---- per-utterance scalars (fp32-exact leave-one-out sims) ----
    if (t < M_UTT) {
        const float sv = red2[t], vv = red2[t + 16];
        const float cc = cn2 - 2.f * sv + vv;      // ||ssum - v||^2
        const float cv = sv - vv;                  // <ssum - v, v>
        const float dc = fmaxf(sqrtf(fmaxf(cc, 0.f)) * (1.f / (M_UTT - 1)), 1e-8f) * (M_UTT - 1);
        const float dv = fmaxf(sqrtf(vv), 1e-8f);
        dterm[spk * M_UTT + t] = (*wp) * (cv / (dc * dv)) + (*bp);
        invs[t] = FP8_SCALE / dv;
    }
    __syncthreads();

    // ---- fp8 outputs (x16 scale) ----
    const float cs = FP8_SCALE / (M_UTT * fmaxf(sqrtf(cn2) * (1.f / M_UTT), 1e-8f));
    {
        int pk = __builtin_amdgcn_cvt_pk_fp8_f32(ss.x * cs, ss.y * cs, 0, false);
        ((unsigned short*)(Cn8 + (size_t)spk * D_EMB))[t] = (unsigned short)pk;
    }
#pragma unroll
    for (int m = 0; m < M_UTT; ++m) {
        const float iv = invs[m];
        int pk = __builtin_amdgcn_cvt_pk_fp8_f32(p[m].x * iv, p[m].y * iv, 0, false);
        ((unsigned short*)(vn8 + ((size_t)(spk * M_UTT + m)) * D_EMB))[t] = (unsigned short)pk;
    }
}

// ---------------------------------------------------------------------------
// Kernel B: MX-scaled fp8 GEMM fused with exp(w'S+b), masking, col-reduce.
// GEMM core = EXACT round-5 config (best measured, 51.8us): single-buffer
// 33KB LDS, serial K-loop, launch_bounds(256,2) -> 4 blocks/CU (the
// VGPR-88/16-wave occupancy optimum; bigger tiles/fewer blocks measured
// worse in rounds 8-11). If done != nullptr, the last block (ticket) also
// computes the final logsumexp sum, replacing finish_kernel's dispatch.
// Ticket pattern is non-blocking -> no deadlock under any dispatch order.
// Coherent colsum re-read via atomicAdd(p,0.f); NO __threadfence (the
// ~310us L2-writeback trap). XCD remap (T1): confirmed -5.4x FETCH.
// Swizzle: granule g of row r at slot g^(r&7), 128B rows.
// ---------------------------------------------------------------------------
__global__ __launch_bounds__(256, 2) void gemm_kernel(
    const unsigned char* __restrict__ Cn8, const unsigned char* __restrict__ vn8,
    const float* __restrict__ wp, const float* __restrict__ bp,
    float* __restrict__ colsum, const float* __restrict__ dterm,
    float* __restrict__ out, int* __restrict__ done)
{
    __shared__ __align__(16) unsigned char As[128 * 128];  // 16KB single buffer
    __shared__ __align__(16) unsigned char Bs[128 * 128];  // 16KB single buffer
    __shared__ float csum[128];
    __shared__ int lastFlag;

    const int tid = threadIdx.x;
    const int w = tid >> 6, l = tid & 63;

    // XCD-aware remap: dispatch-linear id p round-robins across 8 XCDs.
    const int p_lin = blockIdx.x + 16 * blockIdx.y;     // [0, 4096)
    const int L_log = (p_lin & 7) * 512 + (p_lin >> 3); // bijective (4096 % 8 == 0)
    const int by = L_log & 15;    // speaker tile   [0,16)
    const int bx = L_log >> 4;    // utterance tile [0,256)

    const float wgt = (*wp) * (1.f / (FP8_SCALE * FP8_SCALE));
    const float bsc = *bp;

    if (tid < 128) csum[tid] = 0.f;

    // ---- staging geometry: wave w covers rows w*32..w*32+31 of both tiles.
    const int r_l = l >> 3, sl8 = l & 7;
    const int g = sl8 ^ r_l;
    const unsigned char* Ab = Cn8 + (size_t)(by * 128 + w * 32 + r_l) * D_EMB + g * 16;
    const unsigned char* Bb = vn8 + (size_t)(bx * 128 + w * 32 + r_l) * D_EMB + g * 16;
    unsigned char* AsW = As + (w * 32) * 128;
    unsigned char* BsW = Bs + (w * 32) * 128;

    // ---- compute geometry: 2x2 wave grid, each wave 64x64 = 4x4 MFMA (K=128)
    const int wm = w & 1, wn = w >> 1;
    const int l16 = l & 15, q = l >> 4;
    const int s0 = (2 * q) ^ (l & 7);
    const unsigned char* Ard = As + (wm * 64 + l16) * 128;
    const unsigned char* Brd = Bs + (wn * 64 + l16) * 128;

    f32x4 acc[4][4];
    const f32x4 z = {0.f, 0.f, 0.f, 0.f};
#pragma unroll
    for (int i = 0; i < 4; ++i)
#pragma unroll
        for (int j = 0; j < 4; ++j) acc[i][j] = z;

    // ---- simple serial K loop: 4 tiles of BK=128, cross-block TLP hides it
#pragma unroll
    for (int t = 0; t < 4; ++t) {
        const int kk = t * 128;
#pragma unroll
        for (int i = 0; i < 4; ++i) {
            async_copy16(Ab + i * 4096 + kk, AsW + i * 1024);
            async_copy16(Bb + i * 4096 + kk, BsW + i * 1024);
        }
        __syncthreads();   // vmcnt(0) drain + barrier: tile ready
        i32x8 bfr[4];
#pragma unroll
        for (int j = 0; j < 4; ++j) bfr[j] = ld_frag(Brd + j * 2048, s0);
#pragma unroll
        for (int i = 0; i < 4; ++i) {
            i32x8 af = ld_frag(Ard + i * 2048, s0);
#pragma unroll
            for (int j = 0; j < 4; ++j)
                acc[i][j] = __builtin_amdgcn_mfma_scale_f32_16x16x128_f8f6f4(
                    af, bfr[j], acc[i][j], 0, 0, 0, 0x7F7F7F7F, 0, 0x7F7F7F7F);
        }
        __syncthreads();   // all waves done reading before next stage overwrites
    }

    // epilogue: e = exp(w'*dot+b), zero same-speaker entries, reduce over rows.
    // C/D layout (shape-determined): row = q*4 + r, col = l16.
    const int rowg0 = by * 128 + wm * 64 + q * 4;
    const int colg0 = bx * 128 + wn * 64 + l16;
#pragma unroll
    for (int j = 0; j < 4; ++j) {
        const int colg = colg0 + j * 16;
        const int cspk = colg >> 4;       // speaker owning this column
        float p = 0.f;
#pragma unroll
        for (int i = 0; i < 4; ++i) {
            const int rowg = rowg0 + i * 16;
#pragma unroll
            for (int r = 0; r < 4; ++r) {
                float e = __expf(wgt * acc[i][j][r] + bsc);
                p += (rowg + r == cspk) ? 0.f : e;
            }
        }
        p += __shfl_xor(p, 16);
        p += __shfl_xor(p, 32);
        if (q == 0) atomicAdd(&csum[wn * 64 + j * 16 + l16], p);
    }
    __syncthreads();
    if (tid < 128) atomicAdd(&colsum[bx * 128 + tid], csum[tid]);

    // ---- optional fused finisher (only when workspace has the ticket) ----
    if (done != nullptr) {
        asm volatile("s_waitcnt vmcnt(0)" ::: "memory");  // own atomics in L2
        __syncthreads();                                   // ...for ALL threads
        if (tid == 0) {
            int ticket = atomicAdd(done, 1);
            lastFlag = (ticket == GEMM_BLOCKS - 1);
        }
        __syncthreads();
        if (lastFlag) {
            float local = 0.f;
            for (int j = tid; j < NM; j += 256) {
                float td = dterm[j];
                float cs = atomicAdd(&colsum[j], 0.0f);   // device-coherent read
                local += logf(cs + __expf(td)) - td;
            }
#pragma unroll
            for (int off = 32; off > 0; off >>= 1) local += __shfl_xor(local, off);
            if (l == 0) csum[w] = local;   // reuse csum as wave scratch
            __syncthreads();
            if (tid == 0) atomicAdd(out, csum[0] + csum[1] + csum[2] + csum[3]);
        }
    }
}

// ---------------------------------------------------------------------------
// Kernel C (fallback when workspace lacks ticket space):
// L_j = -dterm_j + log(colsum_j + exp(dterm_j)); sum -> out[0]
// ---------------------------------------------------------------------------
__global__ __launch_bounds__(256) void finish_kernel(
    const float* __restrict__ dterm, const float* __restrict__ colsum,
    float* __restrict__ out)
{
    const int idx = blockIdx.x * 256 + threadIdx.x;
    const int stride = gridDim.x * 256;
    float local = 0.f;
    for (int j = idx; j < NM; j += stride) {
        float t = dterm[j];
        local += logf(colsum[j] + __expf(t)) - t;
    }
#pragma unroll
    for (int off = 32; off > 0; off >>= 1) local += __shfl_xor(local, off);
    __shared__ float wr[4];
    const int wave = threadIdx.x >> 6, lane = threadIdx.x & 63;
    if (lane == 0) wr[wave] = local;
    __syncthreads();
    if (threadIdx.x == 0) atomicAdd(out, wr[0] + wr[1] + wr[2] + wr[3]);
}

extern "C" void kernel_launch(void* const* d_in, const int* in_sizes, int n_in,
                              void* d_out, int out_size, void* d_ws, size_t ws_size,
                              hipStream_t stream) {
    const float* V  = (const float*)d_in[0];
    const float* wp = (const float*)d_in[1];
    const float* bp = (const float*)d_in[2];

    char* ws = (char*)d_ws;
    unsigned char* Cn8 = (unsigned char*)ws;                        //  1 MB [2048][512] fp8
    unsigned char* vn8 = (unsigned char*)(ws + ((size_t)1 << 20));  // 16 MB [32768][512] fp8
    float* dterm  = (float*)(ws + ((size_t)17 << 20));              // 128 KB
    float* colsum = dterm + NM;                                     // 128 KB
    float* out    = (float*)d_out;

    // ticket counter lives past the legacy 17MB+256KB layout -- ONLY if the
    // workspace actually has room (rounds 12/13: unchecked OOB write here
    // crashed the container).
    const size_t legacy_end = ((size_t)17 << 20) + (size_t)2 * NM * sizeof(float);
    int* done = (ws_size >= legacy_end + sizeof(int)) ? (int*)(ws + legacy_end)
                                                      : nullptr;

    prep_kernel<<<N_SPK, 256, 0, stream>>>(V, wp, bp, Cn8, vn8, dterm, colsum, out, done);
    gemm_kernel<<<dim3(16, 256), 256, 0, stream>>>(Cn8, vn8, wp, bp, colsum, dterm, out, done);
    if (done == nullptr)
        finish_kernel<<<64, 256, 0, stream>>>(dterm, colsum, out);
}

// Round 15
// 144.581 us; speedup vs baseline: 1.3971x; 1.3971x over previous
//
#include <hip/hip_runtime.h>
#include <stdint.h>

#define N_SPK 2048
#define M_UTT 16
#define D_EMB 512
#define NM (N_SPK * M_UTT)
#define FP8_SCALE 16.0f   // quantization scale for fp8 operands (1/256 folded into w)
#define NBX 256           // utterance tiles; 16 blocks (by) contribute per bx

typedef __attribute__((ext_vector_type(4))) float f32x4;
typedef __attribute__((ext_vector_type(4))) int   i32x4;
typedef __attribute__((ext_vector_type(8))) int   i32x8;

__device__ __forceinline__ void async_copy16(const void* g, void* l) {
    __builtin_amdgcn_global_load_lds(
        (const __attribute__((address_space(1))) unsigned int*)g,
        (__attribute__((address_space(3))) unsigned int*)l,
        16, 0, 0);
}

// read one 32B (K=128) MFMA fragment from swizzled LDS: granule 2q of row r at
// slot s0 = 2q ^ (r&7), granule 2q+1 at s0^1. base points at the 128B row.
__device__ __forceinline__ i32x8 ld_frag(const unsigned char* base, int s0) {
    i32x4 lo = *(const i32x4*)(base + s0 * 16);
    i32x4 hi = *(const i32x4*)(base + (s0 ^ 1) * 16);
    return __builtin_shufflevector(lo, hi, 0, 1, 2, 3, 4, 5, 6, 7);
}

// ---------------------------------------------------------------------------
// Kernel A: per-speaker prep (round-7 34KB-LDS version). Zeroes colsum/out
// and (block 0) the 256 per-bx ticket counters when present.
// ---------------------------------------------------------------------------
__global__ __launch_bounds__(256) void prep_kernel(
    const float* __restrict__ V, const float* __restrict__ wp,
    const float* __restrict__ bp, unsigned char* __restrict__ Cn8,
    unsigned char* __restrict__ vn8, float* __restrict__ dterm,
    float* __restrict__ colsum, float* __restrict__ out,
    int* __restrict__ done)
{
    const int spk = blockIdx.x, t = threadIdx.x;
    const int wave = t >> 6, lane = t & 63;
    const float2* vb = (const float2*)(V + (size_t)spk * (M_UTT * D_EMB)); // [16][256]

    __shared__ __align__(16) float2 red[M_UTT][264];  // {sv,vv} partials (+8 pad)
    __shared__ float red2[32];    // rows 0..15 sv, 16..31 vv
    __shared__ float invs[M_UTT];
    __shared__ float wred[4];

    // folded zeroing of colsum + out + per-bx tickets
    if (spk < 128) colsum[spk * 256 + t] = 0.f;
    if (spk == 0) {
        if (done) done[t] = 0;          // 256 counters, one per bx
        if (t == 0) out[0] = 0.f;
    }

    // ---- single global read pass ----
    float2 p[M_UTT];
#pragma unroll
    for (int m = 0; m < M_UTT; ++m) p[m] = vb[m * 256 + t];

    float2 ss = make_float2(0.f, 0.f);
#pragma unroll
    for (int m = 0; m < M_UTT; ++m) { ss.x += p[m].x; ss.y += p[m].y; }

    // ||ssum||^2 butterfly (4 waves -> wred)
    float cnp = ss.x * ss.x + ss.y * ss.y;
#pragma unroll
    for (int off = 32; off > 0; off >>= 1) cnp += __shfl_xor(cnp, off);
    if (lane == 0) wred[wave] = cnp;

    // per-utterance partials -> LDS (packed sv,vv)
#pragma unroll
    for (int m = 0; m < M_UTT; ++m) {
        red[m][t] = make_float2(ss.x * p[m].x + ss.y * p[m].y,      // <ssum, v> part
                                p[m].x * p[m].x + p[m].y * p[m].y); // ||v||^2 part
    }
    __syncthreads();
    const float cn2 = wred[0] + wred[1] + wred[2] + wred[3];

    // ---- batched row reduction: 16 threads per row, 8 float4 each ----
    {
        const int r = t >> 4, s = t & 15;
        const float4* rp = (const float4*)red;   // row stride = 132 float4
        float sv = 0.f, vvs = 0.f;
#pragma unroll
        for (int k = 0; k < 8; ++k) {
            float4 q = rp[r * 132 + s + 16 * k]; // {sv0,vv0,sv1,vv1}
            sv  += q.x + q.z;
            vvs += q.y + q.w;
        }
        sv  += __shfl_xor(sv, 1);  vvs += __shfl_xor(vvs, 1);
        sv  += __shfl_xor(sv, 2);  vvs += __shfl_xor(vvs, 2);
        sv  += __shfl_xor(sv, 4);  vvs += __shfl_xor(vvs, 4);
        sv  += __shfl_xor(sv, 8);  vvs += __shfl_xor(vvs, 8);
        if (s == 0) { red2[r] = sv; red2[r + 16] = vvs; }
    }
    __syncthreads();

    // ---- per-utterance scalars (fp32-exact leave-one-out sims) ----
    if (t < M_UTT) {
        const float sv = red2[t], vv = red2[t + 16];
        const float cc = cn2 - 2.f * sv + vv;      // ||ssum - v||^2
        const float cv = sv - vv;                  // <ssum - v, v>
        const float dc = fmaxf(sqrtf(fmaxf(cc, 0.f)) * (1.f / (M_UTT - 1)), 1e-8f) * (M_UTT - 1);
        const float dv = fmaxf(sqrtf(vv), 1e-8f);
        dterm[spk * M_UTT + t] = (*wp) * (cv / (dc * dv)) + (*bp);
        invs[t] = FP8_SCALE / dv;
    }
    __syncthreads();

    // ---- fp8 outputs (x16 scale) ----
    const float cs = FP8_SCALE / (M_UTT * fmaxf(sqrtf(cn2) * (1.f / M_UTT), 1e-8f));
    {
        int pk = __builtin_amdgcn_cvt_pk_fp8_f32(ss.x * cs, ss.y * cs, 0, false);
        ((unsigned short*)(Cn8 + (size_t)spk * D_EMB))[t] = (unsigned short)pk;
    }
#pragma unroll
    for (int m = 0; m < M_UTT; ++m) {
        const float iv = invs[m];
        int pk = __builtin_amdgcn_cvt_pk_fp8_f32(p[m].x * iv, p[m].y * iv, 0, false);
        ((unsigned short*)(vn8 + ((size_t)(spk * M_UTT + m)) * D_EMB))[t] = (unsigned short)pk;
    }
}

// ---------------------------------------------------------------------------
// Kernel B: MX-scaled fp8 GEMM fused with exp(w'S+b), masking, col-reduce,
// + PER-BX parallel fused finisher.
// GEMM core = round-5 best (51.8us): single-buffer 33KB LDS, serial K-loop,
// launch_bounds(256,2) -> 4 blocks/CU, VGPR ~88.
// ROUND-14 LESSON: a single last-block finisher is a ~50us SERIAL tail on
// every dispatch (gemm 59->111us). Fix: 256 per-bx tickets -- the 16 blocks
// sharing a bx race; the 16th finishes only its 128 columns (~1us, runs
// CONCURRENTLY with other blocks' gemm). Same proven coherence chain as
// round 14 (correct, absmax 0): colsum atomics -> vmcnt(0) -> ticket ->
// atomicAdd(p,0.f) coherent re-read. Non-blocking; no __threadfence.
// XCD remap (T1): confirmed -5.4x FETCH. Swizzle: granule g of row r at
// slot g^(r&7), 128B rows.
// ---------------------------------------------------------------------------
__global__ __launch_bounds__(256, 2) void gemm_kernel(
    const unsigned char* __restrict__ Cn8, const unsigned char* __restrict__ vn8,
    const float* __restrict__ wp, const float* __restrict__ bp,
    float* __restrict__ colsum, const float* __restrict__ dterm,
    float* __restrict__ out, int* __restrict__ done)
{
    __shared__ __align__(16) unsigned char As[128 * 128];  // 16KB single buffer
    __shared__ __align__(16) unsigned char Bs[128 * 128];  // 16KB single buffer
    __shared__ float csum[128];
    __shared__ int lastFlag;

    const int tid = threadIdx.x;
    const int w = tid >> 6, l = tid & 63;

    // XCD-aware remap: dispatch-linear id p round-robins across 8 XCDs.
    const int p_lin = blockIdx.x + 16 * blockIdx.y;     // [0, 4096)
    const int L_log = (p_lin & 7) * 512 + (p_lin >> 3); // bijective (4096 % 8 == 0)
    const int by = L_log & 15;    // speaker tile   [0,16)
    const int bx = L_log >> 4;    // utterance tile [0,256)

    const float wgt = (*wp) * (1.f / (FP8_SCALE * FP8_SCALE));
    const float bsc = *bp;

    if (tid < 128) csum[tid] = 0.f;

    // ---- staging geometry: wave w covers rows w*32..w*32+31 of both tiles.
    const int r_l = l >> 3, sl8 = l & 7;
    const int g = sl8 ^ r_l;
    const unsigned char* Ab = Cn8 + (size_t)(by * 128 + w * 32 + r_l) * D_EMB + g * 16;
    const unsigned char* Bb = vn8 + (size_t)(bx * 128 + w * 32 + r_l) * D_EMB + g * 16;
    unsigned char* AsW = As + (w * 32) * 128;
    unsigned char* BsW = Bs + (w * 32) * 128;

    // ---- compute geometry: 2x2 wave grid, each wave 64x64 = 4x4 MFMA (K=128)
    const int wm = w & 1, wn = w >> 1;
    const int l16 = l & 15, q = l >> 4;
    const int s0 = (2 * q) ^ (l & 7);
    const unsigned char* Ard = As + (wm * 64 + l16) * 128;
    const unsigned char* Brd = Bs + (wn * 64 + l16) * 128;

    f32x4 acc[4][4];
    const f32x4 z = {0.f, 0.f, 0.f, 0.f};
#pragma unroll
    for (int i = 0; i < 4; ++i)
#pragma unroll
        for (int j = 0; j < 4; ++j) acc[i][j] = z;

    // ---- simple serial K loop: 4 tiles of BK=128, cross-block TLP hides it
#pragma unroll
    for (int t = 0; t < 4; ++t) {
        const int kk = t * 128;
#pragma unroll
        for (int i = 0; i < 4; ++i) {
            async_copy16(Ab + i * 4096 + kk, AsW + i * 1024);
            async_copy16(Bb + i * 4096 + kk, BsW + i * 1024);
        }
        __syncthreads();   // vmcnt(0) drain + barrier: tile ready
        i32x8 bfr[4];
#pragma unroll
        for (int j = 0; j < 4; ++j) bfr[j] = ld_frag(Brd + j * 2048, s0);
#pragma unroll
        for (int i = 0; i < 4; ++i) {
            i32x8 af = ld_frag(Ard + i * 2048, s0);
#pragma unroll
            for (int j = 0; j < 4; ++j)
                acc[i][j] = __builtin_amdgcn_mfma_scale_f32_16x16x128_f8f6f4(
                    af, bfr[j], acc[i][j], 0, 0, 0, 0x7F7F7F7F, 0, 0x7F7F7F7F);
        }
        __syncthreads();   // all waves done reading before next stage overwrites
    }

    // epilogue: e = exp(w'*dot+b), zero same-speaker entries, reduce over rows.
    // C/D layout (shape-determined): row = q*4 + r, col = l16.
    const int rowg0 = by * 128 + wm * 64 + q * 4;
    const int colg0 = bx * 128 + wn * 64 + l16;
#pragma unroll
    for (int j = 0; j < 4; ++j) {
        const int colg = colg0 + j * 16;
        const int cspk = colg >> 4;       // speaker owning this column
        float p = 0.f;
#pragma unroll
        for (int i = 0; i < 4; ++i) {
            const int rowg = rowg0 + i * 16;
#pragma unroll
            for (int r = 0; r < 4; ++r) {
                float e = __expf(wgt * acc[i][j][r] + bsc);
                p += (rowg + r == cspk) ? 0.f : e;
            }
        }
        p += __shfl_xor(p, 16);
        p += __shfl_xor(p, 32);
        if (q == 0) atomicAdd(&csum[wn * 64 + j * 16 + l16], p);
    }
    __syncthreads();
    if (tid < 128) atomicAdd(&colsum[bx * 128 + tid], csum[tid]);

    // ---- per-bx fused finisher: 16th arrival for this bx finishes its
    // 128 columns (parallel across 256 bx tiles, overlapped with gemm work)
    if (done != nullptr) {
        asm volatile("s_waitcnt vmcnt(0)" ::: "memory");  // own atomics at L2
        __syncthreads();                                   // ...for ALL threads
        if (tid == 0)
            lastFlag = (atomicAdd(&done[bx], 1) == 15);
        __syncthreads();
        if (lastFlag) {
            float local = 0.f;
            if (tid < 128) {
                const int j = bx * 128 + tid;
                const float td = dterm[j];
                const float cs2 = atomicAdd(&colsum[j], 0.0f);  // coherent read
                local = logf(cs2 + __expf(td)) - td;
            }
#pragma unroll
            for (int off = 32; off > 0; off >>= 1) local += __shfl_xor(local, off);
            if (l == 0) csum[w] = local;   // reuse csum as wave scratch
            __syncthreads();
            if (tid == 0) atomicAdd(out, csum[0] + csum[1] + csum[2] + csum[3]);
        }
    }
}

// ---------------------------------------------------------------------------
// Kernel C (fallback when workspace lacks ticket space):
// L_j = -dterm_j + log(colsum_j + exp(dterm_j)); sum -> out[0]
// ---------------------------------------------------------------------------
__global__ __launch_bounds__(256) void finish_kernel(
    const float* __restrict__ dterm, const float* __restrict__ colsum,
    float* __restrict__ out)
{
    const int idx = blockIdx.x * 256 + threadIdx.x;
    const int stride = gridDim.x * 256;
    float local = 0.f;
    for (int j = idx; j < NM; j += stride) {
        float t = dterm[j];
        local += logf(colsum[j] + __expf(t)) - t;
    }
#pragma unroll
    for (int off = 32; off > 0; off >>= 1) local += __shfl_xor(local, off);
    __shared__ float wr[4];
    const int wave = threadIdx.x >> 6, lane = threadIdx.x & 63;
    if (lane == 0) wr[wave] = local;
    __syncthreads();
    if (threadIdx.x == 0) atomicAdd(out, wr[0] + wr[1] + wr[2] + wr[3]);
}

extern "C" void kernel_launch(void* const* d_in, const int* in_sizes, int n_in,
                              void* d_out, int out_size, void* d_ws, size_t ws_size,
                              hipStream_t stream) {
    const float* V  = (const float*)d_in[0];
    const float* wp = (const float*)d_in[1];
    const float* bp = (const float*)d_in[2];

    char* ws = (char*)d_ws;
    unsigned char* Cn8 = (unsigned char*)ws;                        //  1 MB [2048][512] fp8
    unsigned char* vn8 = (unsigned char*)(ws + ((size_t)1 << 20));  // 16 MB [32768][512] fp8
    float* dterm  = (float*)(ws + ((size_t)17 << 20));              // 128 KB
    float* colsum = dterm + NM;                                     // 128 KB
    float* out    = (float*)d_out;

    // per-bx ticket array past the legacy layout -- ONLY if ws has room.
    const size_t legacy_end = ((size_t)17 << 20) + (size_t)2 * NM * sizeof(float);
    int* done = (ws_size >= legacy_end + NBX * sizeof(int))
                    ? (int*)(ws + legacy_end) : nullptr;

    prep_kernel<<<N_SPK, 256, 0, stream>>>(V, wp, bp, Cn8, vn8, dterm, colsum, out, done);
    gemm_kernel<<<dim3(16, 256), 256, 0, stream>>>(Cn8, vn8, wp, bp, colsum, dterm, out, done);
    if (done == nullptr)
        finish_kernel<<<64, 256, 0, stream>>>(dterm, colsum, out);
}